// Round 10
// baseline (168.571 us; speedup 1.0000x reference)
//
#include <hip/hip_runtime.h>
#include <hip/hip_bf16.h>

// LoRALinear: y = x @ W^T + b + 1.0 * ((x @ A^T) @ B^T)
// W_eff = W + B@A (bf16, ws[0..2MB)).
// PERSISTENT fused GEMM: grid 256 (1 block/CU), each block computes two
// vertically-adjacent 256x256 tiles (same bn, bm & bm+1) with a SEAMLESS
// 32-iteration K-loop (K wraps at t=16, A-source hops +256 rows; buffer
// parity continuous). One prologue + one drain per CU instead of two.
// Mid-epilogue at the seam: posted stores + acc re-zero.
// Per-tile schedule = R8: 8-phase counted-vmcnt, A (x fp32) reg-staged with
// fused cvt at p3/p4 (1-tile gap), B via global_load_lds 2-ahead,
// counted lgkmcnt(2) gates, XOR bank swizzle, setprio around MFMA.

typedef __bf16 bf16;
typedef bf16 bf16x8 __attribute__((ext_vector_type(8)));
typedef float f32x4 __attribute__((ext_vector_type(4)));

constexpr int K_DIM = 1024;
constexpr int N_DIM = 1024;
constexpr int M_DIM = 8 * 4096;
constexpr int NT2 = 32;  // 2 M-tiles x 16 K-tiles, seamless
constexpr float SCALING = 16.0f / 16.0f;

// ---------------- W_eff = W + B@A, cast to bf16 ----------------
__global__ __launch_bounds__(256) void weff_kernel(
    const float* __restrict__ W, const float* __restrict__ A,
    const float* __restrict__ B, bf16* __restrict__ weff) {
  const int o = blockIdx.x;
  const int tid = threadIdx.x;
  float br[16];
#pragma unroll
  for (int r = 0; r < 16; ++r) br[r] = B[o * 16 + r];
#pragma unroll
  for (int j = 0; j < 4; ++j) {
    const int k = tid + j * 256;
    float s = W[o * K_DIM + k];
#pragma unroll
    for (int r = 0; r < 16; ++r) s += SCALING * br[r] * A[r * K_DIM + k];
    weff[o * K_DIM + k] = (bf16)s;
  }
}

// ---------------- persistent fused 8-phase GEMM ----------------
__device__ __forceinline__ void async16(const void* g, void* l) {
  __builtin_amdgcn_global_load_lds(
      (const __attribute__((address_space(1))) void*)g,
      (__attribute__((address_space(3))) void*)l, 16, 0, 0);
}
#define BAR() __builtin_amdgcn_s_barrier()
#define LGKM(n)                                              \
  do {                                                       \
    asm volatile("s_waitcnt lgkmcnt(" #n ")" ::: "memory");  \
    __builtin_amdgcn_sched_barrier(0);                       \
  } while (0)
#define VMW(n) asm volatile("s_waitcnt vmcnt(" #n ")" ::: "memory")
#define MFMA(d, a, b) d = __builtin_amdgcn_mfma_f32_16x16x32_bf16(a, b, d, 0, 0, 0)

// LDS (bf16 elems): buf c at c*32768; A [0,16384), B [16384,32768).
// Row = 64 bf16 = 8 chunks of 16 B; stored chunk s holds global chunk s^(row&7).

__global__ __launch_bounds__(512, 2) void gemm8p(
    const float* __restrict__ Xf, const bf16* __restrict__ Wf,
    const float* __restrict__ bias, float* __restrict__ Y) {
  __shared__ __align__(16) bf16 smem[65536];  // 128 KiB

  const int tid = threadIdx.x;
  const int lane = tid & 63;
  const int wid = tid >> 6;
  const int wm = wid >> 2;  // 0..1
  const int wn = wid & 3;   // 0..3
  const int l15 = lane & 15;
  const int lq = lane >> 4;

  // XCD-aware bijective swizzle (256 % 8 == 0): per XCD, 8 bm-pairs x 4 bn,
  // bn fastest -> the 4 bn-blocks of one bm stay on one XCD (A-slab L2 reuse).
  const int bid = blockIdx.x;
  const int wgid = (bid & 7) * 32 + (bid >> 3);
  const int pairId = wgid >> 2;  // 0..63
  const int bn = wgid & 3;       // 0..3
  const long m0 = (long)pairId * 512;  // tile 1: rows [m0, m0+256)
  const int n0 = bn * 256;             // tile 2: rows [m0+256, m0+512)

  // ---- B staging (global_load_lds, pre-swizzled source; same panel both tiles)
  const int srow = tid >> 3;               // 0..63
  const int gch = (tid & 7) ^ (srow & 7);  // inverse of read swizzle
  const bf16* wsrc = Wf + (long)(n0 + srow) * K_DIM + gch * 8;
  auto stageB = [&](int tt, int h) {
    bf16* dst = smem + (tt & 1) * 32768 + 16384 + h * 8192 + tid * 8;
    const bf16* s = wsrc + (long)h * 128 * K_DIM + (tt & 15) * 64;
    async16(s, dst);
    async16(s + 64 * K_DIM, dst + 4096);
  };

  // ---- A staging (reg-staged fp32 -> bf16, swizzled ds_write) ----
  const int arow = tid >> 2;  // 0..127
  const int acp = tid & 3;    // chunk pair: global chunks 2acp, 2acp+1
  const int ar7 = arow & 7;
  const int aslot0 = (2 * acp) ^ ar7;
  const int aslot1 = (2 * acp + 1) ^ ar7;
  const float* asrc = Xf + (m0 + arow) * K_DIM + acp * 16;

  auto abase = [&](int tt) {
    // tt>=16 -> second M-tile (rows +256); K offset wraps
    return asrc + (long)(tt >> 4) * 256 * K_DIM + (tt & 15) * 64;
  };

  f32x4 rA0[4], rA1[4];  // single in-flight A set (halves 0/1)
  auto loadA0 = [&](int tt) {
    const float* s = abase(tt);
#pragma unroll
    for (int i = 0; i < 4; ++i) rA0[i] = *(const f32x4*)(s + i * 4);
  };
  auto loadA1 = [&](int tt) {
    const float* s = abase(tt) + (long)128 * K_DIM;
#pragma unroll
    for (int i = 0; i < 4; ++i) rA1[i] = *(const f32x4*)(s + i * 4);
  };
  auto writeA0 = [&](int tt) {  // cvt+write from rA0
    bf16* dst = smem + (tt & 1) * 32768 + arow * 64;
    bf16x8 c0, c1;
#pragma unroll
    for (int j = 0; j < 4; ++j) {
      c0[j] = (bf16)rA0[0][j];
      c0[4 + j] = (bf16)rA0[1][j];
      c1[j] = (bf16)rA0[2][j];
      c1[4 + j] = (bf16)rA0[3][j];
    }
    *(bf16x8*)(dst + aslot0 * 8) = c0;
    *(bf16x8*)(dst + aslot1 * 8) = c1;
  };
  auto writeA1 = [&](int tt) {  // cvt+write from rA1
    bf16* dst = smem + (tt & 1) * 32768 + 8192 + arow * 64;
    bf16x8 c0, c1;
#pragma unroll
    for (int j = 0; j < 4; ++j) {
      c0[j] = (bf16)rA1[0][j];
      c0[4 + j] = (bf16)rA1[1][j];
      c1[j] = (bf16)rA1[2][j];
      c1[4 + j] = (bf16)rA1[3][j];
    }
    *(bf16x8*)(dst + aslot0 * 8) = c0;
    *(bf16x8*)(dst + aslot1 * 8) = c1;
  };

  // fragment read offsets (XOR bank swizzle); kk=1 -> elem offset ^32
  const int key = l15 & 7;
  const int ck0 = lq ^ key;
  const int eA = (wm * 128 + l15) * 64 + ck0 * 8;
  const int eB = (wn * 64 + l15) * 64 + ck0 * 8;

  // epilogue coordinates (C/D layout: col = lane&15, row = lq*4 + reg)
  const long crow0 = m0 + wm * 128 + lq * 4;  // tile 1 row base
  const int ccol0 = n0 + wn * 64 + l15;

  // bias: load ONCE, pin live so the compiler can't sink the loads into the
  // loop (would skew our counted vmcnt bookkeeping).
  float bn4[4];
#pragma unroll
  for (int n = 0; n < 4; ++n) {
    bn4[n] = bias[ccol0 + n * 16];
    asm volatile("" ::"v"(bn4[n]));
  }

  f32x4 acc[8][4] = {};

  // ---- prologue (identical to R8; tt<16 so offsets match) ----
  loadA0(0); loadA1(0);
  stageB(0, 0); stageB(0, 1); stageB(1, 0); stageB(1, 1);
  writeA0(0); writeA1(0);        // cvt waits on loadA(0) only (oldest)
  loadA0(1); loadA1(1);          // rA now holds A(1)
  VMW(12);                       // retire bias+loadA(0)+B(0); keep B(1)+loadA(1)
  asm volatile("s_waitcnt lgkmcnt(0)" ::: "memory");
  BAR();

  for (int t = 0; t < NT2; ++t) {
    // ---- seam: first tile's output complete -> posted stores + acc reset
    if (t == 16) {
#pragma unroll
      for (int m = 0; m < 8; ++m)
#pragma unroll
        for (int n = 0; n < 4; ++n) {
          const int col = ccol0 + n * 16;
#pragma unroll
          for (int i = 0; i < 4; ++i)
            Y[(crow0 + m * 16 + i) * N_DIM + col] = acc[m][n][i] + bn4[n];
        }
#pragma unroll
      for (int m = 0; m < 8; ++m)
#pragma unroll
        for (int n = 0; n < 4; ++n) acc[m][n] = (f32x4)0.0f;
    }

    const bf16* Ab = smem + (t & 1) * 32768;
    const bf16* Bb = Ab + 16384;
    bf16x8 B0[4], B1[4];
    {  // p1: (m0-3, kk0)
      bf16x8 A[4];
#pragma unroll
      for (int i = 0; i < 4; ++i) A[i] = *(const bf16x8*)(Ab + eA + i * 1024);
#pragma unroll
      for (int i = 0; i < 4; ++i) B0[i] = *(const bf16x8*)(Bb + eB + i * 1024);
      BAR();
      LGKM(0);
      __builtin_amdgcn_s_setprio(1);
#pragma unroll
      for (int m = 0; m < 4; ++m)
#pragma unroll
        for (int n = 0; n < 4; ++n) MFMA(acc[m][n], A[m], B0[n]);
      __builtin_amdgcn_s_setprio(0);
      BAR();
    }
    {  // p2: (m0-3, kk1)
      bf16x8 A[4];
#pragma unroll
      for (int i = 0; i < 4; ++i)
        A[i] = *(const bf16x8*)(Ab + (eA ^ 32) + i * 1024);
#pragma unroll
      for (int i = 0; i < 4; ++i)
        B1[i] = *(const bf16x8*)(Bb + (eB ^ 32) + i * 1024);
      BAR();
      LGKM(0);
      __builtin_amdgcn_s_setprio(1);
#pragma unroll
      for (int m = 0; m < 4; ++m)
#pragma unroll
        for (int n = 0; n < 4; ++n) MFMA(acc[m][n], A[m], B1[n]);
      __builtin_amdgcn_s_setprio(0);
      BAR();
    }
    {  // p3: (m4-7, kk0); stage B(t+2) lo; write A(t+1) h0; reload rA0
      bf16x8 A[4];
#pragma unroll
      for (int i = 0; i < 4; ++i)
        A[i] = *(const bf16x8*)(Ab + eA + 4096 + i * 1024);
      __builtin_amdgcn_sched_barrier(0);  // pin: frag reads precede ds_writes
      if (t < NT2 - 2) stageB(t + 2, 0);
      if (t < NT2 - 1) writeA0(t + 1);
      if (t < NT2 - 2) loadA0(t + 2);  // WAR-safe: after cvt reads
      BAR();
      if (t < NT2 - 1) {
        LGKM(2);  // 4 reads done; 2 A-writes retire under MFMA
      } else {
        LGKM(0);
      }
      __builtin_amdgcn_s_setprio(1);
#pragma unroll
      for (int m = 0; m < 4; ++m)
#pragma unroll
        for (int n = 0; n < 4; ++n) MFMA(acc[4 + m][n], A[m], B0[n]);
      __builtin_amdgcn_s_setprio(0);
      BAR();
    }
    {  // p4: (m4-7, kk1); stage B(t+2) hi; write A(t+1) h1; reload rA1
      bf16x8 A[4];
#pragma unroll
      for (int i = 0; i < 4; ++i)
        A[i] = *(const bf16x8*)(Ab + (eA ^ 32) + 4096 + i * 1024);
      __builtin_amdgcn_sched_barrier(0);  // pin: frag reads precede ds_writes
      if (t < NT2 - 2) stageB(t + 2, 1);
      if (t < NT2 - 1) writeA1(t + 1);
      if (t < NT2 - 2) loadA1(t + 2);
      BAR();
      if (t < NT2 - 1) {
        LGKM(2);  // p3 writes + p4 reads done; p4's 2 writes outstanding
      } else {
        LGKM(0);
      }
      __builtin_amdgcn_s_setprio(1);
#pragma unroll
      for (int m = 0; m < 4; ++m)
#pragma unroll
        for (int n = 0; n < 4; ++n) MFMA(acc[4 + m][n], A[m], B1[n]);
      __builtin_amdgcn_s_setprio(0);
      // drain this tile's A-writes before the boundary barrier (cross-wave
      // visibility); they retired under the MFMA cluster.
      if (t < NT2 - 1) LGKM(0);
      // boundary: everything older than stageB(t+2)+loadA(t+2) (12 newest)
      // must retire. At the seam the mid-stores are older -> L2-ack drains
      // them once (~cheap, issued 4 phases earlier).
      if (t < NT2 - 2) {
        VMW(12);
      } else if (t == NT2 - 2) {
        VMW(0);
      }
      BAR();
    }
  }

  // ---- final epilogue: second tile (rows +256) ----
#pragma unroll
  for (int m = 0; m < 8; ++m)
#pragma unroll
    for (int n = 0; n < 4; ++n) {
      const int col = ccol0 + n * 16;
#pragma unroll
      for (int i = 0; i < 4; ++i)
        Y[(crow0 + 256 + m * 16 + i) * N_DIM + col] = acc[m][n][i] + bn4[n];
    }
}

extern "C" void kernel_launch(void* const* d_in, const int* in_sizes, int n_in,
                              void* d_out, int out_size, void* d_ws, size_t ws_size,
                              hipStream_t stream) {
  const float* x = (const float*)d_in[0];
  const float* W = (const float*)d_in[1];
  const float* b = (const float*)d_in[2];
  const float* lA = (const float*)d_in[3];
  const float* lB = (const float*)d_in[4];
  float* y = (float*)d_out;

  bf16* weff = (bf16*)d_ws;  // 2 MB

  weff_kernel<<<dim3(1024), dim3(256), 0, stream>>>(W, lA, lB, weff);

  const int grid = (M_DIM / 512) * (N_DIM / 256);  // 64 pairs * 4 = 256
  gemm8p<<<dim3(grid), dim3(512), 0, stream>>>(x, weff, b, y);
}

// Round 11
// 109.103 us; speedup vs baseline: 1.5451x; 1.5451x over previous
//
#include <hip/hip_runtime.h>
#include <hip/hip_bf16.h>

// LoRALinear: y = x @ W^T + b + 1.0 * ((x @ A^T) @ B^T)
// W_eff = W + B@A (bf16, ws[0..2MB)).
// Fused GEMM 256x256x64, R10: 2 MERGED phases per K-tile (32 MFMA per
// barrier-pair) and NO sched_barrier pins (compiler free to interleave the
// cvt/stage work with MFMA clusters; m141 evidence). Counted waits kept:
//   P2 gate LGKM(4) -> 4 A-ds_writes retire under the MFMA cluster;
//   boundary LGKM(0) (cross-wave ds_write visibility) + VMW(12) (counted,
//   steady-state no-op; real sync is the cvt-dependency FIFO retire).
// A (x fp32) reg-staged with fused fp32->bf16 cvt, 1-tile gap (R5/R8);
// B via global_load_lds staged 2 tiles ahead (B region dead after P1).

typedef __bf16 bf16;
typedef bf16 bf16x8 __attribute__((ext_vector_type(8)));
typedef float f32x4 __attribute__((ext_vector_type(4)));

constexpr int K_DIM = 1024;
constexpr int N_DIM = 1024;
constexpr int M_DIM = 8 * 4096;
constexpr int NT = K_DIM / 64;  // 16 K-tiles
constexpr float SCALING = 16.0f / 16.0f;

// ---------------- W_eff = W + B@A, cast to bf16 ----------------
__global__ __launch_bounds__(256) void weff_kernel(
    const float* __restrict__ W, const float* __restrict__ A,
    const float* __restrict__ B, bf16* __restrict__ weff) {
  const int o = blockIdx.x;
  const int tid = threadIdx.x;
  float br[16];
#pragma unroll
  for (int r = 0; r < 16; ++r) br[r] = B[o * 16 + r];
#pragma unroll
  for (int j = 0; j < 4; ++j) {
    const int k = tid + j * 256;
    float s = W[o * K_DIM + k];
#pragma unroll
    for (int r = 0; r < 16; ++r) s += SCALING * br[r] * A[r * K_DIM + k];
    weff[o * K_DIM + k] = (bf16)s;
  }
}

// ---------------- fused 2-phase 256x256 GEMM ----------------
__device__ __forceinline__ void async16(const void* g, void* l) {
  __builtin_amdgcn_global_load_lds(
      (const __attribute__((address_space(1))) void*)g,
      (__attribute__((address_space(3))) void*)l, 16, 0, 0);
}
#define BAR() __builtin_amdgcn_s_barrier()
// asm-"memory" waitcnt: compiler-level fence (stops ds ops crossing) with a
// counted runtime wait. NO sched_barrier (m141: pinning defeats scheduling).
#define LGKM(n) asm volatile("s_waitcnt lgkmcnt(" #n ")" ::: "memory")
#define VMW(n) asm volatile("s_waitcnt vmcnt(" #n ")" ::: "memory")
#define MFMA(d, a, b) d = __builtin_amdgcn_mfma_f32_16x16x32_bf16(a, b, d, 0, 0, 0)

// LDS (bf16 elems): buf c at c*32768; A [0,16384), B [16384,32768).
// Row = 64 bf16 = 8 chunks of 16 B; stored chunk s holds global chunk s^(row&7).

__global__ __launch_bounds__(512, 2) void gemm2p(
    const float* __restrict__ Xf, const bf16* __restrict__ Wf,
    const float* __restrict__ bias, float* __restrict__ Y) {
  __shared__ __align__(16) bf16 smem[65536];  // 128 KiB

  const int tid = threadIdx.x;
  const int lane = tid & 63;
  const int wid = tid >> 6;
  const int wm = wid >> 2;  // 0..1
  const int wn = wid & 3;   // 0..3
  const int l15 = lane & 15;
  const int lq = lane >> 4;

  // XCD-aware bijective swizzle (512 % 8 == 0)
  const int bid = blockIdx.x;
  const int wgid = (bid & 7) * 64 + (bid >> 3);
  const int bm = wgid >> 2;  // 0..127
  const int bn = wgid & 3;   // 0..3
  const long m0 = (long)bm * 256;
  const int n0 = bn * 256;

  // ---- B staging (global_load_lds, pre-swizzled source) ----
  const int srow = tid >> 3;               // 0..63
  const int gch = (tid & 7) ^ (srow & 7);  // inverse of read swizzle
  const bf16* wsrc = Wf + (long)(n0 + srow) * K_DIM + gch * 8;
  auto stageB = [&](int tt, int h) {
    bf16* dst = smem + (tt & 1) * 32768 + 16384 + h * 8192 + tid * 8;
    const bf16* s = wsrc + (long)h * 128 * K_DIM + tt * 64;
    async16(s, dst);
    async16(s + 64 * K_DIM, dst + 4096);
  };

  // ---- A staging (reg-staged fp32 -> bf16, swizzled ds_write) ----
  const int arow = tid >> 2;  // 0..127
  const int acp = tid & 3;    // chunk pair: global chunks 2acp, 2acp+1
  const int ar7 = arow & 7;
  const int aslot0 = (2 * acp) ^ ar7;
  const int aslot1 = (2 * acp + 1) ^ ar7;
  const float* asrc = Xf + (m0 + arow) * K_DIM + acp * 16;

  f32x4 rA0[4], rA1[4];  // single in-flight A set (halves 0/1)
  auto loadA0 = [&](int tt) {
    const float* s = asrc + tt * 64;
#pragma unroll
    for (int i = 0; i < 4; ++i) rA0[i] = *(const f32x4*)(s + i * 4);
  };
  auto loadA1 = [&](int tt) {
    const float* s = asrc + (long)128 * K_DIM + tt * 64;
#pragma unroll
    for (int i = 0; i < 4; ++i) rA1[i] = *(const f32x4*)(s + i * 4);
  };
  auto writeA0 = [&](int tt) {  // cvt+write from rA0
    bf16* dst = smem + (tt & 1) * 32768 + arow * 64;
    bf16x8 c0, c1;
#pragma unroll
    for (int j = 0; j < 4; ++j) {
      c0[j] = (bf16)rA0[0][j];
      c0[4 + j] = (bf16)rA0[1][j];
      c1[j] = (bf16)rA0[2][j];
      c1[4 + j] = (bf16)rA0[3][j];
    }
    *(bf16x8*)(dst + aslot0 * 8) = c0;
    *(bf16x8*)(dst + aslot1 * 8) = c1;
  };
  auto writeA1 = [&](int tt) {  // cvt+write from rA1
    bf16* dst = smem + (tt & 1) * 32768 + 8192 + arow * 64;
    bf16x8 c0, c1;
#pragma unroll
    for (int j = 0; j < 4; ++j) {
      c0[j] = (bf16)rA1[0][j];
      c0[4 + j] = (bf16)rA1[1][j];
      c1[j] = (bf16)rA1[2][j];
      c1[4 + j] = (bf16)rA1[3][j];
    }
    *(bf16x8*)(dst + aslot0 * 8) = c0;
    *(bf16x8*)(dst + aslot1 * 8) = c1;
  };

  // fragment read offsets (XOR bank swizzle); kk=1 -> elem offset ^32
  const int key = l15 & 7;
  const int ck0 = lq ^ key;
  const int eA = (wm * 128 + l15) * 64 + ck0 * 8;
  const int eB = (wn * 64 + l15) * 64 + ck0 * 8;

  f32x4 acc[8][4] = {};

  // ---- prologue (R8) ----
  loadA0(0); loadA1(0);
  stageB(0, 0); stageB(0, 1); stageB(1, 0); stageB(1, 1);
  writeA0(0); writeA1(0);        // cvt waits on loadA(0) only (oldest)
  loadA0(1); loadA1(1);          // rA now holds A(1)
  VMW(12);                       // retire B(0); keep B(1)+loadA(1) in flight
  LGKM(0);
  BAR();

  for (int t = 0; t < NT; ++t) {
    const bf16* Ab = smem + (t & 1) * 32768;
    const bf16* Bb = Ab + 16384;
    bf16x8 B0[4], B1[4];
    {  // P1: m0-3, both kk; reads A0/A1 + ALL B frags
      bf16x8 A0[4], A1[4];
#pragma unroll
      for (int i = 0; i < 4; ++i) {
        A0[i] = *(const bf16x8*)(Ab + eA + i * 1024);
        A1[i] = *(const bf16x8*)(Ab + (eA ^ 32) + i * 1024);
      }
#pragma unroll
      for (int i = 0; i < 4; ++i) {
        B0[i] = *(const bf16x8*)(Bb + eB + i * 1024);
        B1[i] = *(const bf16x8*)(Bb + (eB ^ 32) + i * 1024);
      }
      BAR();
      LGKM(0);
      __builtin_amdgcn_s_setprio(1);
#pragma unroll
      for (int m = 0; m < 4; ++m)
#pragma unroll
        for (int n = 0; n < 4; ++n) MFMA(acc[m][n], A0[m], B0[n]);
#pragma unroll
      for (int m = 0; m < 4; ++m)
#pragma unroll
        for (int n = 0; n < 4; ++n) MFMA(acc[m][n], A1[m], B1[n]);
      __builtin_amdgcn_s_setprio(0);
      BAR();
    }
    {  // P2: m4-7 (B held in regs) + ALL staging; counted gates
      bf16x8 A0[4], A1[4];
#pragma unroll
      for (int i = 0; i < 4; ++i) {
        A0[i] = *(const bf16x8*)(Ab + eA + 4096 + i * 1024);
        A1[i] = *(const bf16x8*)(Ab + (eA ^ 32) + 4096 + i * 1024);
      }
      if (t < NT - 2) { stageB(t + 2, 0); stageB(t + 2, 1); }
      if (t < NT - 1) { writeA0(t + 1); writeA1(t + 1); }
      if (t < NT - 2) { loadA0(t + 2); loadA1(t + 2); }  // WAR-safe: after cvt
      BAR();
      if (t < NT - 1) {
        LGKM(4);  // 8 reads done; 4 A-writes retire under MFMA
      } else {
        LGKM(0);
      }
      __builtin_amdgcn_s_setprio(1);
#pragma unroll
      for (int m = 0; m < 4; ++m)
#pragma unroll
        for (int n = 0; n < 4; ++n) MFMA(acc[4 + m][n], A0[m], B0[n]);
#pragma unroll
      for (int m = 0; m < 4; ++m)
#pragma unroll
        for (int n = 0; n < 4; ++n) MFMA(acc[4 + m][n], A1[m], B1[n]);
      __builtin_amdgcn_s_setprio(0);
      // drain A-writes (cross-wave visibility for next tile's P1 reads)
      if (t < NT - 1) LGKM(0);
      // boundary: B(t+1) already retired via writeA's cvt-dependency FIFO;
      // 12 newest (stageB(t+2) 4 + loadA(t+2) 8) stay in flight.
      if (t < NT - 2) {
        VMW(12);
      } else if (t == NT - 2) {
        VMW(0);
      }
      BAR();
    }
  }

  // epilogue: C/D layout col = lane&15, row = lq*4 + reg
  const long crow0 = m0 + wm * 128 + lq * 4;
  const int ccol0 = n0 + wn * 64 + l15;
  float bn4[4];
#pragma unroll
  for (int n = 0; n < 4; ++n) bn4[n] = bias[ccol0 + n * 16];
#pragma unroll
  for (int m = 0; m < 8; ++m)
#pragma unroll
    for (int n = 0; n < 4; ++n) {
      const int col = ccol0 + n * 16;
#pragma unroll
      for (int i = 0; i < 4; ++i)
        Y[(crow0 + m * 16 + i) * N_DIM + col] = acc[m][n][i] + bn4[n];
    }
}

extern "C" void kernel_launch(void* const* d_in, const int* in_sizes, int n_in,
                              void* d_out, int out_size, void* d_ws, size_t ws_size,
                              hipStream_t stream) {
  const float* x = (const float*)d_in[0];
  const float* W = (const float*)d_in[1];
  const float* b = (const float*)d_in[2];
  const float* lA = (const float*)d_in[3];
  const float* lB = (const float*)d_in[4];
  float* y = (float*)d_out;

  bf16* weff = (bf16*)d_ws;  // 2 MB

  weff_kernel<<<dim3(1024), dim3(256), 0, stream>>>(W, lA, lB, weff);

  const int grid = (M_DIM / 256) * (N_DIM / 256);  // 512
  gemm2p<<<dim3(grid), dim3(512), 0, stream>>>(x, weff, b, y);
}

// Round 12
// 100.531 us; speedup vs baseline: 1.6768x; 1.0853x over previous
//
#include <hip/hip_runtime.h>
#include <hip/hip_bf16.h>

// LoRALinear: y = x @ W^T + b + 1.0 * ((x @ A^T) @ B^T)
// W_eff = W + B@A (bf16, ws[0..2MB)).
// Fused GEMM 256x256x64, R11: TWO barriers per K-tile (mid + boundary) and
// NO forced post-barrier lgkm gates -- compiler emits fine-grained lgkmcnt
// for frag-read->MFMA deps (m97 asm evidence). Forced LGKM(0) only
// post-MFMA (nearly free): pre-mid (guards B-region write-after-read
// cross-wave) and pre-boundary (A ds_write visibility). Counted VMW(12)
// boundary unchanged (R10 FIFO walk).
// A (x fp32) reg-staged with fused fp32->bf16 cvt, 1-tile gap (R5/R8);
// B via global_load_lds staged 2 tiles ahead (B region dead after P1 --
// B0/B1 held in regs across the tile).

typedef __bf16 bf16;
typedef bf16 bf16x8 __attribute__((ext_vector_type(8)));
typedef float f32x4 __attribute__((ext_vector_type(4)));

constexpr int K_DIM = 1024;
constexpr int N_DIM = 1024;
constexpr int M_DIM = 8 * 4096;
constexpr int NT = K_DIM / 64;  // 16 K-tiles
constexpr float SCALING = 16.0f / 16.0f;

// ---------------- W_eff = W + B@A, cast to bf16 ----------------
__global__ __launch_bounds__(256) void weff_kernel(
    const float* __restrict__ W, const float* __restrict__ A,
    const float* __restrict__ B, bf16* __restrict__ weff) {
  const int o = blockIdx.x;
  const int tid = threadIdx.x;
  float br[16];
#pragma unroll
  for (int r = 0; r < 16; ++r) br[r] = B[o * 16 + r];
#pragma unroll
  for (int j = 0; j < 4; ++j) {
    const int k = tid + j * 256;
    float s = W[o * K_DIM + k];
#pragma unroll
    for (int r = 0; r < 16; ++r) s += SCALING * br[r] * A[r * K_DIM + k];
    weff[o * K_DIM + k] = (bf16)s;
  }
}

// ---------------- fused 2-barrier 256x256 GEMM ----------------
__device__ __forceinline__ void async16(const void* g, void* l) {
  __builtin_amdgcn_global_load_lds(
      (const __attribute__((address_space(1))) void*)g,
      (__attribute__((address_space(3))) void*)l, 16, 0, 0);
}
#define BAR() __builtin_amdgcn_s_barrier()
#define LGKM(n) asm volatile("s_waitcnt lgkmcnt(" #n ")" ::: "memory")
#define VMW(n) asm volatile("s_waitcnt vmcnt(" #n ")" ::: "memory")
#define MFMA(d, a, b) d = __builtin_amdgcn_mfma_f32_16x16x32_bf16(a, b, d, 0, 0, 0)

// LDS (bf16 elems): buf c at c*32768; A [0,16384), B [16384,32768).
// Row = 64 bf16 = 8 chunks of 16 B; stored chunk s holds global chunk s^(row&7).

__global__ __launch_bounds__(512, 2) void gemm2b(
    const float* __restrict__ Xf, const bf16* __restrict__ Wf,
    const float* __restrict__ bias, float* __restrict__ Y) {
  __shared__ __align__(16) bf16 smem[65536];  // 128 KiB

  const int tid = threadIdx.x;
  const int lane = tid & 63;
  const int wid = tid >> 6;
  const int wm = wid >> 2;  // 0..1
  const int wn = wid & 3;   // 0..3
  const int l15 = lane & 15;
  const int lq = lane >> 4;

  // XCD-aware bijective swizzle (512 % 8 == 0)
  const int bid = blockIdx.x;
  const int wgid = (bid & 7) * 64 + (bid >> 3);
  const int bm = wgid >> 2;  // 0..127
  const int bn = wgid & 3;   // 0..3
  const long m0 = (long)bm * 256;
  const int n0 = bn * 256;

  // ---- B staging (global_load_lds, pre-swizzled source) ----
  const int srow = tid >> 3;               // 0..63
  const int gch = (tid & 7) ^ (srow & 7);  // inverse of read swizzle
  const bf16* wsrc = Wf + (long)(n0 + srow) * K_DIM + gch * 8;
  auto stageB = [&](int tt, int h) {
    bf16* dst = smem + (tt & 1) * 32768 + 16384 + h * 8192 + tid * 8;
    const bf16* s = wsrc + (long)h * 128 * K_DIM + tt * 64;
    async16(s, dst);
    async16(s + 64 * K_DIM, dst + 4096);
  };

  // ---- A staging (reg-staged fp32 -> bf16, swizzled ds_write) ----
  const int arow = tid >> 2;  // 0..127
  const int acp = tid & 3;    // chunk pair: global chunks 2acp, 2acp+1
  const int ar7 = arow & 7;
  const int aslot0 = (2 * acp) ^ ar7;
  const int aslot1 = (2 * acp + 1) ^ ar7;
  const float* asrc = Xf + (m0 + arow) * K_DIM + acp * 16;

  f32x4 rA0[4], rA1[4];  // single in-flight A set (halves 0/1)
  auto loadA0 = [&](int tt) {
    const float* s = asrc + tt * 64;
#pragma unroll
    for (int i = 0; i < 4; ++i) rA0[i] = *(const f32x4*)(s + i * 4);
  };
  auto loadA1 = [&](int tt) {
    const float* s = asrc + (long)128 * K_DIM + tt * 64;
#pragma unroll
    for (int i = 0; i < 4; ++i) rA1[i] = *(const f32x4*)(s + i * 4);
  };
  auto writeA0 = [&](int tt) {  // cvt+write from rA0
    bf16* dst = smem + (tt & 1) * 32768 + arow * 64;
    bf16x8 c0, c1;
#pragma unroll
    for (int j = 0; j < 4; ++j) {
      c0[j] = (bf16)rA0[0][j];
      c0[4 + j] = (bf16)rA0[1][j];
      c1[j] = (bf16)rA0[2][j];
      c1[4 + j] = (bf16)rA0[3][j];
    }
    *(bf16x8*)(dst + aslot0 * 8) = c0;
    *(bf16x8*)(dst + aslot1 * 8) = c1;
  };
  auto writeA1 = [&](int tt) {  // cvt+write from rA1
    bf16* dst = smem + (tt & 1) * 32768 + 8192 + arow * 64;
    bf16x8 c0, c1;
#pragma unroll
    for (int j = 0; j < 4; ++j) {
      c0[j] = (bf16)rA1[0][j];
      c0[4 + j] = (bf16)rA1[1][j];
      c1[j] = (bf16)rA1[2][j];
      c1[4 + j] = (bf16)rA1[3][j];
    }
    *(bf16x8*)(dst + aslot0 * 8) = c0;
    *(bf16x8*)(dst + aslot1 * 8) = c1;
  };

  // fragment read offsets (XOR bank swizzle); kk=1 -> elem offset ^32
  const int key = l15 & 7;
  const int ck0 = lq ^ key;
  const int eA = (wm * 128 + l15) * 64 + ck0 * 8;
  const int eB = (wn * 64 + l15) * 64 + ck0 * 8;

  f32x4 acc[8][4] = {};

  // ---- prologue (R8/R10) ----
  loadA0(0); loadA1(0);
  stageB(0, 0); stageB(0, 1); stageB(1, 0); stageB(1, 1);
  writeA0(0); writeA1(0);        // cvt waits on loadA(0) only (oldest)
  loadA0(1); loadA1(1);          // rA now holds A(1)
  VMW(12);                       // retire B(0); keep B(1)+loadA(1) in flight
  LGKM(0);
  BAR();

  for (int t = 0; t < NT; ++t) {
    const bf16* Ab = smem + (t & 1) * 32768;
    const bf16* Bb = Ab + 16384;
    {  // P1: m0-3, both kk. Reads issue; compiler inserts fine lgkm waits.
      bf16x8 B0[4], B1[4], A0[4], A1[4];
#pragma unroll
      for (int i = 0; i < 4; ++i) {
        B0[i] = *(const bf16x8*)(Bb + eB + i * 1024);
        B1[i] = *(const bf16x8*)(Bb + (eB ^ 32) + i * 1024);
        A0[i] = *(const bf16x8*)(Ab + eA + i * 1024);
        A1[i] = *(const bf16x8*)(Ab + (eA ^ 32) + i * 1024);
      }
      __builtin_amdgcn_s_setprio(1);
#pragma unroll
      for (int m = 0; m < 4; ++m)
#pragma unroll
        for (int n = 0; n < 4; ++n) MFMA(acc[m][n], A0[m], B0[n]);
#pragma unroll
      for (int m = 0; m < 4; ++m)
#pragma unroll
        for (int n = 0; n < 4; ++n) MFMA(acc[m][n], A1[m], B1[n]);
      __builtin_amdgcn_s_setprio(0);
      // drain ALL P1 reads (incl. any the compiler deferred) so stageB's
      // LDS writes after the mid barrier can't clobber unread B-region.
      LGKM(0);
      BAR();  // mid
      // P2: m4-7 (B0/B1 from regs) + all staging for t+1/t+2.
      bf16x8 C0[4], C1[4];
#pragma unroll
      for (int i = 0; i < 4; ++i) {
        C0[i] = *(const bf16x8*)(Ab + eA + 4096 + i * 1024);
        C1[i] = *(const bf16x8*)(Ab + (eA ^ 32) + 4096 + i * 1024);
      }
      if (t < NT - 2) { stageB(t + 2, 0); stageB(t + 2, 1); }
      if (t < NT - 1) { writeA0(t + 1); writeA1(t + 1); }  // cvt: vmcnt(8) FIFO
      if (t < NT - 2) { loadA0(t + 2); loadA1(t + 2); }    // WAR-safe
      __builtin_amdgcn_s_setprio(1);
#pragma unroll
      for (int m = 0; m < 4; ++m)
#pragma unroll
        for (int n = 0; n < 4; ++n) MFMA(acc[4 + m][n], C0[m], B0[n]);
#pragma unroll
      for (int m = 0; m < 4; ++m)
#pragma unroll
        for (int n = 0; n < 4; ++n) MFMA(acc[4 + m][n], C1[m], B1[n]);
      __builtin_amdgcn_s_setprio(0);
      // drain A ds_writes (cross-wave visibility at next tile's P1 reads);
      // they retired under the MFMA cluster.
      LGKM(0);
      // boundary: B(t+1) already retired via writeA's cvt-dependency FIFO;
      // 12 newest (stageB(t+2) 4 + loadA(t+2) 8) stay in flight.
      if (t < NT - 2) {
        VMW(12);
      } else if (t == NT - 2) {
        VMW(0);
      }
      BAR();  // boundary
    }
  }

  // epilogue: C/D layout col = lane&15, row = lq*4 + reg
  const long crow0 = m0 + wm * 128 + lq * 4;
  const int ccol0 = n0 + wn * 64 + l15;
  float bn4[4];
#pragma unroll
  for (int n = 0; n < 4; ++n) bn4[n] = bias[ccol0 + n * 16];
#pragma unroll
  for (int m = 0; m < 8; ++m)
#pragma unroll
    for (int n = 0; n < 4; ++n) {
      const int col = ccol0 + n * 16;
#pragma unroll
      for (int i = 0; i < 4; ++i)
        Y[(crow0 + m * 16 + i) * N_DIM + col] = acc[m][n][i] + bn4[n];
    }
}

extern "C" void kernel_launch(void* const* d_in, const int* in_sizes, int n_in,
                              void* d_out, int out_size, void* d_ws, size_t ws_size,
                              hipStream_t stream) {
  const float* x = (const float*)d_in[0];
  const float* W = (const float*)d_in[1];
  const float* b = (const float*)d_in[2];
  const float* lA = (const float*)d_in[3];
  const float* lB = (const float*)d_in[4];
  float* y = (float*)d_out;

  bf16* weff = (bf16*)d_ws;  // 2 MB

  weff_kernel<<<dim3(1024), dim3(256), 0, stream>>>(W, lA, lB, weff);

  const int grid = (M_DIM / 256) * (N_DIM / 256);  // 512
  gemm2b<<<dim3(grid), dim3(512), 0, stream>>>(x, weff, b, y);
}